// Round 7
// baseline (1871.668 us; speedup 1.0000x reference)
//
#include <hip/hip_runtime.h>
#include <stdint.h>

#define HDIM 128
#define NGRID 262144
#define NMESH 40962
#define NEDGE 524288

typedef __attribute__((ext_vector_type(8))) short short8;
typedef __attribute__((ext_vector_type(16))) float f32x16;
typedef unsigned int u32;
typedef unsigned long long u64;

// ---- ws layout (byte offsets) ----
#define WS_COUNT   0x000000u
#define WS_ROWPTR  0x100000u
#define WS_WLOC    0x200010u
#define WS_BSUM    0x300100u
#define WS_SORTED  0x310000u
#define WS_WEIGHTS 0x800000u
// weight section offsets in u16 units:
#define WE1 0u
#define WE2 49152u
#define WN1 65536u
#define WN2 98304u

static __device__ __forceinline__ u32 f2bf_u(float f) {
  union { float f; u32 u; } v; v.f = f;
  u32 u = v.u;
  u += 0x7fffu + ((u >> 16) & 1u);
  return u >> 16;
}
static __device__ __forceinline__ unsigned short f2bf(float f) { return (unsigned short)f2bf_u(f); }
static __device__ __forceinline__ u32 pack2bf(float a, float b) {
  return f2bf_u(a) | (f2bf_u(b) << 16);
}
static __device__ __forceinline__ short8 cvt8(const float* p) {
  float4 f0 = *(const float4*)p;
  float4 f1 = *(const float4*)(p + 4);
  short8 r;
  r[0] = (short)f2bf_u(f0.x); r[1] = (short)f2bf_u(f0.y);
  r[2] = (short)f2bf_u(f0.z); r[3] = (short)f2bf_u(f0.w);
  r[4] = (short)f2bf_u(f1.x); r[5] = (short)f2bf_u(f1.y);
  r[6] = (short)f2bf_u(f1.z); r[7] = (short)f2bf_u(f1.w);
  return r;
}

union U8 { unsigned int u[4]; short8 s; };

// build the two GEMM2 B-frags (windows 2c, 2c+1) from silu'd accumulator block a
static __device__ __forceinline__ void buildB2(const f32x16& a, int hi, U8& f0, U8& f1) {
  #pragma unroll
  for (int h = 0; h < 2; ++h) {
    unsigned P1a = pack2bf(a[8 * h + 0], a[8 * h + 1]);
    unsigned P1b = pack2bf(a[8 * h + 2], a[8 * h + 3]);
    unsigned P2a = pack2bf(a[8 * h + 4], a[8 * h + 5]);
    unsigned P2b = pack2bf(a[8 * h + 6], a[8 * h + 7]);
    unsigned sA = hi ? P1a : P2a, sB = hi ? P1b : P2b;
    unsigned rA = (unsigned)__shfl_xor((int)sA, 32);
    unsigned rB = (unsigned)__shfl_xor((int)sB, 32);
    U8& f = h ? f1 : f0;
    f.u[0] = hi ? rA : P1a;
    f.u[1] = hi ? rB : P1b;
    f.u[2] = hi ? P2a : rA;
    f.u[3] = hi ? P2b : rB;
  }
}

// ---- pack weights frag-major for 32x32x16: frag (w,ks), lane-contiguous 16B ----
__global__ void pack_weights(const float* __restrict__ eW1, const float* __restrict__ eW2,
                             const float* __restrict__ nW1, const float* __restrict__ nW2,
                             unsigned short* __restrict__ wp)
{
  int i = blockIdx.x * 256 + threadIdx.x;
  const float* W; int KS; u32 base; int j;
  if (i < 49152)       { W = eW1; KS = 24; base = WE1; j = i; }
  else if (i < 65536)  { W = eW2; KS = 8;  base = WE2; j = i - 49152; }
  else if (i < 98304)  { W = nW1; KS = 16; base = WN1; j = i - 65536; }
  else if (i < 114688) { W = nW2; KS = 8;  base = WN2; j = i - 98304; }
  else return;
  int ii = j & 7, l = (j >> 3) & 63, frag = j >> 9;
  int ks = frag % KS, w = frag / KS;
  int row = w * 32 + (l & 31);
  int k = ks * 16 + (l >> 5) * 8 + ii;
  wp[base + j] = f2bf(W[(size_t)k * 128 + row]);
}

__global__ void hist_k(const int* __restrict__ dst, u32* __restrict__ cnt) {
  int e = blockIdx.x * 256 + threadIdx.x;
  atomicAdd(&cnt[dst[e]], 1u);
}

__global__ void scan1(const u32* __restrict__ cnt, u32* __restrict__ rp, u32* __restrict__ bsum) {
  int t = threadIdx.x, b = blockIdx.x;
  int i0 = b * 1024 + t * 4;
  uint4 v = *(const uint4*)(cnt + i0);
  u32 s = v.x + v.y + v.z + v.w;
  u32 sc = s;
  #pragma unroll
  for (int d = 1; d < 64; d <<= 1) {
    u32 n = (u32)__shfl_up((int)sc, d);
    if ((t & 63) >= d) sc += n;
  }
  __shared__ u32 wsum[4];
  if ((t & 63) == 63) wsum[t >> 6] = sc;
  __syncthreads();
  u32 woff = 0;
  for (int w = 0; w < (t >> 6); ++w) woff += wsum[w];
  u32 ex = woff + sc - s;
  rp[i0] = ex; rp[i0 + 1] = ex + v.x; rp[i0 + 2] = ex + v.x + v.y; rp[i0 + 3] = ex + v.x + v.y + v.z;
  if (t == 255) bsum[b] = woff + sc;
}

__global__ void scan2(u32* __restrict__ bsum) {
  int t = threadIdx.x;
  u32 s = bsum[t];
  u32 sc = s;
  #pragma unroll
  for (int d = 1; d < 64; d <<= 1) {
    u32 n = (u32)__shfl_up((int)sc, d);
    if ((t & 63) >= d) sc += n;
  }
  __shared__ u32 wsum[4];
  if ((t & 63) == 63) wsum[t >> 6] = sc;
  __syncthreads();
  u32 woff = 0;
  for (int w = 0; w < (t >> 6); ++w) woff += wsum[w];
  bsum[t] = woff + sc - s;
}

__global__ void scan3(u32* __restrict__ rp, u32* __restrict__ wloc, const u32* __restrict__ bsum) {
  int t = threadIdx.x, b = blockIdx.x;
  int i0 = b * 1024 + t * 4;
  u32 off = bsum[b];
  #pragma unroll
  for (int j = 0; j < 4; ++j) { u32 vv = rp[i0 + j] + off; rp[i0 + j] = vv; wloc[i0 + j] = vv; }
  if (b == 0 && t == 0) rp[NGRID] = NEDGE;
}

__global__ void scatter_k(const int* __restrict__ src, const int* __restrict__ dst,
                          u32* __restrict__ wloc, u64* __restrict__ sorted) {
  int e = blockIdx.x * 256 + threadIdx.x;
  int d = dst[e];
  u32 pos = atomicAdd(&wloc[d], 1u);
  sorted[pos] = (u64)(u32)src[e] | ((u64)(u32)d << 16) | ((u64)(u32)e << 34);
}

// ---- fused: block = 128 grid nodes; each wave owns 32 nodes + their edges.
//      Wave-private agg slice, zero barriers. launch_bounds(.,1): full VGPR budget. ----
__global__ __launch_bounds__(256, 1)
void fused_kernel(const float* __restrict__ ef, const float* __restrict__ gridf,
                  const float* __restrict__ mesh,
                  const unsigned short* __restrict__ wp,
                  const float* __restrict__ eb1, const float* __restrict__ eb2,
                  const float* __restrict__ elng, const float* __restrict__ elnb,
                  const float* __restrict__ nb1, const float* __restrict__ nb2,
                  const float* __restrict__ nlng, const float* __restrict__ nlnb,
                  const u32* __restrict__ rowptr, const u64* __restrict__ sorted,
                  float* __restrict__ out)
{
  __shared__ float aggLDS[4][32 * 129];   // 66 KB; one 16.5 KB slice per wave

  const int tid = threadIdx.x;
  const int wv = tid >> 6, ln = tid & 63, l31 = ln & 31, hi = ln >> 5;
  const int nb = blockIdx.x * 128 + wv * 32;        // wave's first node
  const int rs = (int)rowptr[nb], re = (int)rowptr[nb + 32];
  float* aggw = aggLDS[wv];

  for (int i = ln; i < 32 * 129; i += 64) aggw[i] = 0.f;

  const short8* A1 = (const short8*)(wp + WE1);
  const short8* A2 = (const short8*)(wp + WE2);

  // -------- edge loop: wave-private 32-edge tiles --------
  for (int base = rs; base < re; base += 32) {
    int p = base + l31;
    const bool valid = p < re;
    if (!valid) p = re - 1;
    const u64 sv = sorted[p];
    const int dl = (int)((sv >> 16) & 0x3ffffu) - nb;
    const float* rowS = mesh  + (size_t)(sv & 0xffffu) * HDIM;
    const float* rowD = gridf + (size_t)(nb + dl) * HDIM;
    const float* rowE = ef    + (size_t)(sv >> 34) * HDIM;

    // GEMM1: h1[128 cols x 32 edges], K=384, 4 independent chains
    f32x16 a1[4];
    #pragma unroll
    for (int c = 0; c < 4; ++c) a1[c] = (f32x16)(0.f);
    #pragma unroll
    for (int ks = 0; ks < 24; ++ks) {
      const float* bp = (ks < 8) ? (rowS + ks * 16)
                      : (ks < 16) ? (rowD + (ks - 8) * 16)
                                  : (rowE + (ks - 16) * 16);
      short8 B = cvt8(bp + hi * 8);
      #pragma unroll
      for (int c = 0; c < 4; ++c)
        a1[c] = __builtin_amdgcn_mfma_f32_32x32x16_bf16(A1[(c * 24 + ks) * 64 + ln], B, a1[c], 0, 0, 0);
    }

    // progressive: silu block c -> 2 B2 frags -> accumulate into a2 -> a1[c] dies
    f32x16 a2[4];
    #pragma unroll
    for (int c = 0; c < 4; ++c) a2[c] = (f32x16)(0.f);
    #pragma unroll
    for (int c = 0; c < 4; ++c) {
      #pragma unroll
      for (int q = 0; q < 4; ++q) {
        float4 b1q = *(const float4*)(eb1 + 32 * c + 8 * q + 4 * hi);
        #pragma unroll
        for (int i = 0; i < 4; ++i) {
          float x = a1[c][q * 4 + i] + b1q[i];
          a1[c][q * 4 + i] = x / (1.f + __expf(-x));
        }
      }
      U8 f0, f1;
      buildB2(a1[c], hi, f0, f1);
      #pragma unroll
      for (int c2 = 0; c2 < 4; ++c2) {
        a2[c2] = __builtin_amdgcn_mfma_f32_32x32x16_bf16(A2[(c2 * 8 + 2 * c) * 64 + ln], f0.s, a2[c2], 0, 0, 0);
        a2[c2] = __builtin_amdgcn_mfma_f32_32x32x16_bf16(A2[(c2 * 8 + 2 * c + 1) * 64 + ln], f1.s, a2[c2], 0, 0, 0);
      }
    }

    // +b2, LN over 128 outcols (64 in-lane + partner)
    float vs = 0.f, vq = 0.f;
    #pragma unroll
    for (int c2 = 0; c2 < 4; ++c2) {
      #pragma unroll
      for (int q = 0; q < 4; ++q) {
        float4 b2q = *(const float4*)(eb2 + 32 * c2 + 8 * q + 4 * hi);
        #pragma unroll
        for (int i = 0; i < 4; ++i) {
          float x = a2[c2][q * 4 + i] + b2q[i];
          a2[c2][q * 4 + i] = x;
          vs += x; vq += x * x;
        }
      }
    }
    vs += __shfl_xor(vs, 32);
    vq += __shfl_xor(vq, 32);
    float mean = vs * (1.f / 128.f);
    float rstd = rsqrtf(vq * (1.f / 128.f) - mean * mean + 1e-5f);

    // LN scale/shift + ef residual, masked wave-private LDS scatter-add
    #pragma unroll
    for (int c2 = 0; c2 < 4; ++c2) {
      #pragma unroll
      for (int q = 0; q < 4; ++q) {
        int colb = 32 * c2 + 8 * q + 4 * hi;
        float4 g4 = *(const float4*)(elng + colb);
        float4 bb4 = *(const float4*)(elnb + colb);
        float4 e4 = *(const float4*)(rowE + colb);
        float v0 = e4.x + (a2[c2][q * 4 + 0] - mean) * rstd * g4.x + bb4.x;
        float v1 = e4.y + (a2[c2][q * 4 + 1] - mean) * rstd * g4.y + bb4.y;
        float v2 = e4.z + (a2[c2][q * 4 + 2] - mean) * rstd * g4.z + bb4.z;
        float v3 = e4.w + (a2[c2][q * 4 + 3] - mean) * rstd * g4.w + bb4.w;
        if (valid) {
          float* ap = &aggw[dl * 129 + colb];
          atomicAdd(ap + 0, v0);
          atomicAdd(ap + 1, v1);
          atomicAdd(ap + 2, v2);
          atomicAdd(ap + 3, v3);
        }
      }
    }
  }

  // -------- node phase: wave-private 32 nodes --------
  const short8* AN1 = (const short8*)(wp + WN1);
  const short8* AN2 = (const short8*)(wp + WN2);
  const float* rowG = gridf + (size_t)(nb + l31) * HDIM;

  f32x16 a1[4];
  #pragma unroll
  for (int c = 0; c < 4; ++c) a1[c] = (f32x16)(0.f);
  #pragma unroll
  for (int ks = 0; ks < 16; ++ks) {
    short8 B;
    if (ks < 8) {
      B = cvt8(rowG + ks * 16 + hi * 8);
    } else {
      const float* ap = aggw + l31 * 129 + (ks - 8) * 16 + hi * 8;
      short8 t;
      #pragma unroll
      for (int i = 0; i < 8; ++i) t[i] = (short)f2bf_u(ap[i]);
      B = t;
    }
    #pragma unroll
    for (int c = 0; c < 4; ++c)
      a1[c] = __builtin_amdgcn_mfma_f32_32x32x16_bf16(AN1[(c * 16 + ks) * 64 + ln], B, a1[c], 0, 0, 0);
  }

  f32x16 a2[4];
  #pragma unroll
  for (int c = 0; c < 4; ++c) a2[c] = (f32x16)(0.f);
  #pragma unroll
  for (int c = 0; c < 4; ++c) {
    #pragma unroll
    for (int q = 0; q < 4; ++q) {
      float4 b1q = *(const float4*)(nb1 + 32 * c + 8 * q + 4 * hi);
      #pragma unroll
      for (int i = 0; i < 4; ++i) {
        float x = a1[c][q * 4 + i] + b1q[i];
        a1[c][q * 4 + i] = x / (1.f + __expf(-x));
      }
    }
    U8 f0, f1;
    buildB2(a1[c], hi, f0, f1);
    #pragma unroll
    for (int c2 = 0; c2 < 4; ++c2) {
      a2[c2] = __builtin_amdgcn_mfma_f32_32x32x16_bf16(AN2[(c2 * 8 + 2 * c) * 64 + ln], f0.s, a2[c2], 0, 0, 0);
      a2[c2] = __builtin_amdgcn_mfma_f32_32x32x16_bf16(AN2[(c2 * 8 + 2 * c + 1) * 64 + ln], f1.s, a2[c2], 0, 0, 0);
    }
  }

  float vs = 0.f, vq = 0.f;
  #pragma unroll
  for (int c2 = 0; c2 < 4; ++c2) {
    #pragma unroll
    for (int q = 0; q < 4; ++q) {
      float4 b2q = *(const float4*)(nb2 + 32 * c2 + 8 * q + 4 * hi);
      #pragma unroll
      for (int i = 0; i < 4; ++i) {
        float x = a2[c2][q * 4 + i] + b2q[i];
        a2[c2][q * 4 + i] = x;
        vs += x; vq += x * x;
      }
    }
  }
  vs += __shfl_xor(vs, 32);
  vq += __shfl_xor(vq, 32);
  float mean = vs * (1.f / 128.f);
  float rstd = rsqrtf(vq * (1.f / 128.f) - mean * mean + 1e-5f);

  #pragma unroll
  for (int c2 = 0; c2 < 4; ++c2) {
    #pragma unroll
    for (int q = 0; q < 4; ++q) {
      int colb = 32 * c2 + 8 * q + 4 * hi;
      float4 g4 = *(const float4*)(nlng + colb);
      float4 bb4 = *(const float4*)(nlnb + colb);
      float4 gr = *(const float4*)(rowG + colb);
      float4 res;
      res.x = gr.x + (a2[c2][q * 4 + 0] - mean) * rstd * g4.x + bb4.x;
      res.y = gr.y + (a2[c2][q * 4 + 1] - mean) * rstd * g4.y + bb4.y;
      res.z = gr.z + (a2[c2][q * 4 + 2] - mean) * rstd * g4.z + bb4.z;
      res.w = gr.w + (a2[c2][q * 4 + 3] - mean) * rstd * g4.w + bb4.w;
      *(float4*)(out + (size_t)(nb + l31) * HDIM + colb) = res;
    }
  }
}

extern "C" void kernel_launch(void* const* d_in, const int* in_sizes, int n_in,
                              void* d_out, int out_size, void* d_ws, size_t ws_size,
                              hipStream_t stream)
{
  (void)in_sizes; (void)n_in; (void)out_size; (void)ws_size;
  const float* ef   = (const float*)d_in[0];
  const float* grid = (const float*)d_in[1];
  const float* mesh = (const float*)d_in[2];
  const float* eW1  = (const float*)d_in[3];
  const float* eb1  = (const float*)d_in[4];
  const float* eW2  = (const float*)d_in[5];
  const float* eb2  = (const float*)d_in[6];
  const float* elng = (const float*)d_in[7];
  const float* elnb = (const float*)d_in[8];
  const float* nW1  = (const float*)d_in[9];
  const float* nb1  = (const float*)d_in[10];
  const float* nW2  = (const float*)d_in[11];
  const float* nb2  = (const float*)d_in[12];
  const float* nlng = (const float*)d_in[13];
  const float* nlnb = (const float*)d_in[14];
  const int* src    = (const int*)d_in[15];
  const int* dst    = (const int*)d_in[16];
  float* out = (float*)d_out;

  unsigned char* wsb = (unsigned char*)d_ws;
  u32* cnt  = (u32*)(wsb + WS_COUNT);
  u32* rp   = (u32*)(wsb + WS_ROWPTR);
  u32* wloc = (u32*)(wsb + WS_WLOC);
  u32* bsum = (u32*)(wsb + WS_BSUM);
  u64* sorted = (u64*)(wsb + WS_SORTED);
  unsigned short* wp = (unsigned short*)(wsb + WS_WEIGHTS);

  hipMemsetAsync(cnt, 0, (size_t)NGRID * 4, stream);
  pack_weights<<<448, 256, 0, stream>>>(eW1, eW2, nW1, nW2, wp);
  hist_k<<<NEDGE / 256, 256, 0, stream>>>(dst, cnt);
  scan1<<<256, 256, 0, stream>>>(cnt, rp, bsum);
  scan2<<<1, 256, 0, stream>>>(bsum);
  scan3<<<256, 256, 0, stream>>>(rp, wloc, bsum);
  scatter_k<<<NEDGE / 256, 256, 0, stream>>>(src, dst, wloc, sorted);
  fused_kernel<<<NGRID / 128, 256, 0, stream>>>(ef, grid, mesh, wp,
      eb1, eb2, elng, elnb, nb1, nb2, nlng, nlnb, rp, sorted, out);
}

// Round 9
// 926.076 us; speedup vs baseline: 2.0211x; 2.0211x over previous
//
#include <hip/hip_runtime.h>
#include <stdint.h>

#define HDIM 128
#define NGRID 262144
#define NMESH 40962
#define NEDGE 524288

typedef __attribute__((ext_vector_type(8))) short short8;
typedef __attribute__((ext_vector_type(4))) float f32x4;
typedef unsigned int u32;
typedef unsigned long long u64;

// ---- ws layout (byte offsets) ----
#define WS_COUNT   0x000000u
#define WS_ROWPTR  0x100000u
#define WS_WLOC    0x200010u
#define WS_BSUM    0x300100u
#define WS_SORTED  0x310000u   // u64[NEDGE] (4 MB)
#define WS_WEIGHTS 0x800000u   // u16[114688] (224 KB)
#define WS_ESORT   0x840000u   // bf16[NEDGE][128] (134 MB)
// weight section offsets in u16 units:
#define WE1 0u
#define WE2 49152u
#define WN1 65536u
#define WN2 98304u

static __device__ __forceinline__ u32 f2bf_u(float f) {
  union { float f; u32 u; } v; v.f = f;
  u32 u = v.u;
  u += 0x7fffu + ((u >> 16) & 1u);
  return u >> 16;
}
static __device__ __forceinline__ unsigned short f2bf(float f) { return (unsigned short)f2bf_u(f); }
static __device__ __forceinline__ float bf2f(unsigned short h) {
  union { u32 u; float f; } v; v.u = ((u32)h) << 16;
  return v.f;
}
static __device__ __forceinline__ short8 cvt8(const float* p) {
  float4 f0 = *(const float4*)p;
  float4 f1 = *(const float4*)(p + 4);
  short8 r;
  r[0] = (short)f2bf_u(f0.x); r[1] = (short)f2bf_u(f0.y);
  r[2] = (short)f2bf_u(f0.z); r[3] = (short)f2bf_u(f0.w);
  r[4] = (short)f2bf_u(f1.x); r[5] = (short)f2bf_u(f1.y);
  r[6] = (short)f2bf_u(f1.z); r[7] = (short)f2bf_u(f1.w);
  return r;
}

// ---- pack weights: fp32 [K][128] -> bf16 transposed [col][K] (R2 layout) ----
__global__ void pack_weights(const float* __restrict__ eW1, const float* __restrict__ eW2,
                             const float* __restrict__ nW1, const float* __restrict__ nW2,
                             unsigned short* __restrict__ wp)
{
  int i = blockIdx.x * 256 + threadIdx.x;
  if (i < 49152) {                 // eW1T [128][384]
    int c = i / 384, k = i % 384;
    wp[WE1 + i] = f2bf(eW1[(size_t)k * 128 + c]);
  } else if (i < 65536) {          // eW2T [128][128]
    int j = i - 49152; int c = j / 128, k = j % 128;
    wp[WE2 + j] = f2bf(eW2[(size_t)k * 128 + c]);
  } else if (i < 98304) {          // nW1T [128][256]
    int j = i - 65536; int c = j / 256, k = j % 256;
    wp[WN1 + j] = f2bf(nW1[(size_t)k * 128 + c]);
  } else if (i < 114688) {         // nW2T [128][128]
    int j = i - 98304; int c = j / 128, k = j % 128;
    wp[WN2 + j] = f2bf(nW2[(size_t)k * 128 + c]);
  }
}

__global__ void hist_k(const int* __restrict__ dst, u32* __restrict__ cnt) {
  int e = blockIdx.x * 256 + threadIdx.x;
  atomicAdd(&cnt[dst[e]], 1u);
}

__global__ void scan1(const u32* __restrict__ cnt, u32* __restrict__ rp, u32* __restrict__ bsum) {
  int t = threadIdx.x, b = blockIdx.x;
  int i0 = b * 1024 + t * 4;
  uint4 v = *(const uint4*)(cnt + i0);
  u32 s = v.x + v.y + v.z + v.w;
  u32 sc = s;
  #pragma unroll
  for (int d = 1; d < 64; d <<= 1) {
    u32 n = (u32)__shfl_up((int)sc, d);
    if ((t & 63) >= d) sc += n;
  }
  __shared__ u32 wsum[4];
  if ((t & 63) == 63) wsum[t >> 6] = sc;
  __syncthreads();
  u32 woff = 0;
  for (int w = 0; w < (t >> 6); ++w) woff += wsum[w];
  u32 ex = woff + sc - s;
  rp[i0] = ex; rp[i0 + 1] = ex + v.x; rp[i0 + 2] = ex + v.x + v.y; rp[i0 + 3] = ex + v.x + v.y + v.z;
  if (t == 255) bsum[b] = woff + sc;
}

__global__ void scan2(u32* __restrict__ bsum) {
  int t = threadIdx.x;
  u32 s = bsum[t];
  u32 sc = s;
  #pragma unroll
  for (int d = 1; d < 64; d <<= 1) {
    u32 n = (u32)__shfl_up((int)sc, d);
    if ((t & 63) >= d) sc += n;
  }
  __shared__ u32 wsum[4];
  if ((t & 63) == 63) wsum[t >> 6] = sc;
  __syncthreads();
  u32 woff = 0;
  for (int w = 0; w < (t >> 6); ++w) woff += wsum[w];
  bsum[t] = woff + sc - s;
}

__global__ void scan3(u32* __restrict__ rp, u32* __restrict__ wloc, const u32* __restrict__ bsum) {
  int t = threadIdx.x, b = blockIdx.x;
  int i0 = b * 1024 + t * 4;
  u32 off = bsum[b];
  #pragma unroll
  for (int j = 0; j < 4; ++j) { u32 vv = rp[i0 + j] + off; rp[i0 + j] = vv; wloc[i0 + j] = vv; }
  if (b == 0 && t == 0) rp[NGRID] = NEDGE;
}

__global__ void scatter_k(const int* __restrict__ src, const int* __restrict__ dst,
                          u32* __restrict__ wloc, u64* __restrict__ sorted) {
  int e = blockIdx.x * 256 + threadIdx.x;
  int d = dst[e];
  u32 pos = atomicAdd(&wloc[d], 1u);
  sorted[pos] = (u64)(u32)src[e] | ((u64)(u32)d << 16) | ((u64)(u32)e << 34);
}

// ---- edge kernel: sorted order, row-side MFMA (R2 datapath), writes e_feats at sorted pos ----
template<bool SORTEDOUT>
__global__ __launch_bounds__(256, 4)
void edge_kernel(const float* __restrict__ ef, const float* __restrict__ gridf,
                 const float* __restrict__ mesh, const unsigned short* __restrict__ wp,
                 const float* __restrict__ b1, const float* __restrict__ b2,
                 const float* __restrict__ lng, const float* __restrict__ lnb,
                 const u64* __restrict__ sorted,
                 unsigned short* __restrict__ esort, float* __restrict__ aggf)
{
  __shared__ __align__(16) unsigned short h1s[64][136];

  const int tid  = threadIdx.x;
  const int wave = tid >> 6, lane = tid & 63, l16 = lane & 15, g4 = lane >> 4;
  const int e0   = blockIdx.x * 64;
  const int arow = wave * 16 + l16;

  const u64 sv = sorted[e0 + arow];
  const float* rowS = mesh  + (size_t)(sv & 0xffffu) * HDIM;
  const float* rowD = gridf + (size_t)((sv >> 16) & 0x3ffffu) * HDIM;
  const float* rowE = ef    + (size_t)(sv >> 34) * HDIM;

  const unsigned short* wl1 = wp + WE1 + (size_t)l16 * 384 + g4 * 8;
  const unsigned short* wl2 = wp + WE2 + (size_t)l16 * 128 + g4 * 8;

  // ---- GEMM1: K=384 ----
  f32x4 acc[8];
  #pragma unroll
  for (int c = 0; c < 8; ++c) acc[c] = (f32x4){0.f, 0.f, 0.f, 0.f};
  #pragma unroll
  for (int ks = 0; ks < 12; ++ks) {
    const float* base = (ks < 4) ? rowS : (ks < 8) ? rowD : rowE;
    short8 a = cvt8(base + (ks & 3) * 32 + g4 * 8);
    #pragma unroll
    for (int c = 0; c < 8; ++c) {
      short8 b = *(const short8*)(wl1 + (size_t)c * 16 * 384 + ks * 32);
      acc[c] = __builtin_amdgcn_mfma_f32_16x16x32_bf16(a, b, acc[c], 0, 0, 0);
    }
  }

  // ---- silu, pair-pack to h1s (wave-private rows) ----
  #pragma unroll
  for (int c = 0; c < 8; ++c) {
    const int col = c * 16 + l16;
    float bb = b1[col];
    #pragma unroll
    for (int r = 0; r < 4; ++r) {
      float x = acc[c][r] + bb;
      float s = x / (1.f + __expf(-x));
      unsigned h = f2bf_u(s);
      unsigned other = (unsigned)__shfl_xor((int)h, 1);
      unsigned packed = (l16 & 1) ? ((h << 16) | other) : ((other << 16) | h);
      if ((l16 & 1) == (r & 1)) {
        *(u32*)(&h1s[wave * 16 + g4 * 4 + r][col & ~1]) = packed;
      }
    }
  }

  // ---- GEMM2: K=128 ----
  f32x4 acc2[8];
  #pragma unroll
  for (int c = 0; c < 8; ++c) acc2[c] = (f32x4){0.f, 0.f, 0.f, 0.f};
  #pragma unroll
  for (int ks = 0; ks < 4; ++ks) {
    short8 a = *(const short8*)(&h1s[arow][ks * 32 + g4 * 8]);
    #pragma unroll
    for (int c = 0; c < 8; ++c) {
      short8 b = *(const short8*)(wl2 + (size_t)c * 16 * 128 + ks * 32);
      acc2[c] = __builtin_amdgcn_mfma_f32_16x16x32_bf16(a, b, acc2[c], 0, 0, 0);
    }
  }

  // ---- +b2, LN ----
  float vs[4] = {0.f, 0.f, 0.f, 0.f};
  float vq[4] = {0.f, 0.f, 0.f, 0.f};
  #pragma unroll
  for (int c = 0; c < 8; ++c) {
    float bb = b2[c * 16 + l16];
    #pragma unroll
    for (int r = 0; r < 4; ++r) {
      float x = acc2[c][r] + bb;
      acc2[c][r] = x;
      vs[r] += x; vq[r] += x * x;
    }
  }
  #pragma unroll
  for (int m = 1; m < 16; m <<= 1) {
    #pragma unroll
    for (int r = 0; r < 4; ++r) {
      vs[r] += __shfl_xor(vs[r], m);
      vq[r] += __shfl_xor(vq[r], m);
    }
  }
  float mean[4], rstd[4];
  #pragma unroll
  for (int r = 0; r < 4; ++r) {
    mean[r] = vs[r] * (1.f / 128.f);
    float var = vq[r] * (1.f / 128.f) - mean[r] * mean[r];
    rstd[r] = rsqrtf(var + 1e-5f);
  }

  // per-row sorted entries (from lane holding that row)
  u64 svr[4];
  #pragma unroll
  for (int r = 0; r < 4; ++r) svr[r] = (u64)__shfl((long long)sv, g4 * 4 + r);

  #pragma unroll
  for (int c = 0; c < 8; ++c) {
    const int col = c * 16 + l16;
    float gg = lng[col], bb = lnb[col];
    #pragma unroll
    for (int r = 0; r < 4; ++r) {
      const int row = wave * 16 + g4 * 4 + r;
      float y = (acc2[c][r] - mean[r]) * rstd[r] * gg + bb
              + ef[(size_t)(svr[r] >> 34) * HDIM + col];
      if (SORTEDOUT) {
        unsigned h = f2bf_u(y);
        unsigned other = (unsigned)__shfl_xor((int)h, 1);
        unsigned packed = (l16 & 1) ? ((h << 16) | other) : ((other << 16) | h);
        if ((l16 & 1) == (r & 1)) {
          *(u32*)(&h1s[row][col & ~1]) = packed;
        }
      } else {
        unsafeAtomicAdd(&aggf[(size_t)((svr[r] >> 16) & 0x3ffffu) * HDIM + col], y);
      }
    }
  }

  if (SORTEDOUT) {
    __syncthreads();
    // coalesced copy-out: 64 rows x 256 B (4 threads/row x 64 B each)
    const int row = tid >> 2, ch = tid & 3;
    uint4* d = (uint4*)(esort + (size_t)(e0 + row) * HDIM + ch * 32);
    const uint4* s = (const uint4*)(&h1s[row][ch * 32]);
    d[0] = s[0]; d[1] = s[1]; d[2] = s[2]; d[3] = s[3];
  }
}

// ---- node kernel: contiguous e_feat row sums + R2 node MLP ----
template<bool FROMWS>
__global__ __launch_bounds__(256, 3)
void node_kernel(const float* __restrict__ gridf, const unsigned short* __restrict__ wp,
                 const float* __restrict__ b1, const float* __restrict__ b2,
                 const float* __restrict__ lng, const float* __restrict__ lnb,
                 const u32* __restrict__ rowptr, const unsigned short* __restrict__ esort,
                 const float* __restrict__ aggf, float* __restrict__ out)
{
  __shared__ __align__(16) unsigned short h1s[64][136];

  const int tid  = threadIdx.x;
  const int wave = tid >> 6, lane = tid & 63, l16 = lane & 15, g4 = lane >> 4;
  const int n0   = blockIdx.x * 64;
  const int arow = wave * 16 + l16;
  const int n    = n0 + arow;
  const float* rowG = gridf + (size_t)n * HDIM;

  // agg = sum of this node's contiguous e_feat rows (lane's k-slices only)
  float sm[4][8];
  #pragma unroll
  for (int kk = 0; kk < 4; ++kk)
    #pragma unroll
    for (int i = 0; i < 8; ++i) sm[kk][i] = 0.f;

  if (FROMWS) {
    const u32 rs = rowptr[n], re = rowptr[n + 1];
    for (u32 p = rs; p < re; ++p) {
      const unsigned short* rp8 = esort + (size_t)p * HDIM + g4 * 8;
      #pragma unroll
      for (int kk = 0; kk < 4; ++kk) {
        short8 v = *(const short8*)(rp8 + kk * 32);
        #pragma unroll
        for (int i = 0; i < 8; ++i) sm[kk][i] += bf2f((unsigned short)v[i]);
      }
    }
  } else {
    #pragma unroll
    for (int kk = 0; kk < 4; ++kk) {
      const float* ap = aggf + (size_t)n * HDIM + kk * 32 + g4 * 8;
      #pragma unroll
      for (int i = 0; i < 8; ++i) sm[kk][i] = ap[i];
    }
  }

  const unsigned short* wl1 = wp + WN1 + (size_t)l16 * 256 + g4 * 8;
  const unsigned short* wl2 = wp + WN2 + (size_t)l16 * 128 + g4 * 8;

  // ---- GEMM1: K=256 ----
  f32x4 acc[8];
  #pragma unroll
  for (int c = 0; c < 8; ++c) acc[c] = (f32x4){0.f, 0.f, 0.f, 0.f};
  #pragma unroll
  for (int ks = 0; ks < 8; ++ks) {
    short8 a;
    if (ks < 4) {
      a = cvt8(rowG + ks * 32 + g4 * 8);
    } else {
      short8 t;
      #pragma unroll
      for (int i = 0; i < 8; ++i) t[i] = (short)f2bf_u(sm[ks - 4][i]);
      a = t;
    }
    #pragma unroll
    for (int c = 0; c < 8; ++c) {
      short8 b = *(const short8*)(wl1 + (size_t)c * 16 * 256 + ks * 32);
      acc[c] = __builtin_amdgcn_mfma_f32_16x16x32_bf16(a, b, acc[c], 0, 0, 0);
    }
  }

  #pragma unroll
  for (int c = 0; c < 8; ++c) {
    const int col = c * 16 + l16;
    float bb = b1[col];
    #pragma unroll
    for (int r = 0; r < 4; ++r) {
      float x = acc[c][r] + bb;
      float s = x / (1.f + __expf(-x));
      unsigned h = f2bf_u(s);
      unsigned other = (unsigned)__shfl_xor((int)h, 1);
      unsigned packed = (l16 & 1) ? ((h << 16) | other) : ((other << 16) | h);
      if ((l16 & 1) == (r & 1)) {
        *(u32*)(&h1s[wave * 16 + g4 * 4 + r][col & ~1]) = packed;
      }
    }
  }

  // ---- GEMM2: K=128 ----
  f32x4 acc2[8];
  #pragma unroll
  for (int c = 0; c < 8; ++c) acc2[c] = (f32x4){0.f, 0.f, 0.f, 0.f};
  #pragma unroll
  for (int ks = 0; ks < 4; ++ks) {
    short8 a = *(const short8*)(&h1s[arow][ks * 32 + g4 * 8]);
    #pragma unroll
    for (int c = 0; c < 8; ++c) {
      short8 b = *(const short8*)(wl2 + (size_t)c * 16 * 128 + ks * 32);
      acc2[c] = __builtin_amdgcn_mfma_f32_16x16x32_bf16(a, b, acc2[c], 0, 0, 0);
    }
  }

  // ---- +b2, LN, +grid residual, store ----
  float vs[4] = {0.f, 0.f, 0.f, 0.f};
  float vq[4] = {0.f, 0.f, 0.f, 0.f};
  #pragma unroll
  for (int c = 0; c < 8; ++c) {
    float bb = b2[c * 16 + l16];
    #pragma unroll
    for (int r = 0; r < 4; ++r) {
      float x = acc2[c][r] + bb;
      acc2[c][r] = x;
      vs[r] += x; vq[r] += x * x;
    }
  }
  #pragma unroll
  for (int m = 1; m < 16; m <<= 1) {
    #pragma unroll
    for (int r = 0; r < 4; ++r) {
      vs[r] += __shfl_xor(vs[r], m);
      vq[r] += __shfl_xor(vq[r], m);
    }
  }
  float mean[4], rstd[4];
  #pragma unroll
  for (int r = 0; r < 4; ++r) {
    mean[r] = vs[r] * (1.f / 128.f);
    float var = vq[r] * (1.f / 128.f) - mean[r] * mean[r];
    rstd[r] = rsqrtf(var + 1e-5f);
  }
  #pragma unroll
  for (int c = 0; c < 8; ++c) {
    const int col = c * 16 + l16;
    float gg = lng[col], bb = lnb[col];
    #pragma unroll
    for (int r = 0; r < 4; ++r) {
      const int row = wave * 16 + g4 * 4 + r;
      size_t idx = (size_t)(n0 + row) * HDIM + col;
      float y = (acc2[c][r] - mean[r]) * rstd[r] * gg + bb;
      out[idx] = gridf[idx] + y;
    }
  }
}

extern "C" void kernel_launch(void* const* d_in, const int* in_sizes, int n_in,
                              void* d_out, int out_size, void* d_ws, size_t ws_size,
                              hipStream_t stream)
{
  (void)in_sizes; (void)n_in; (void)out_size;
  const float* ef   = (const float*)d_in[0];
  const float* grid = (const float*)d_in[1];
  const float* mesh = (const float*)d_in[2];
  const float* eW1  = (const float*)d_in[3];
  const float* eb1  = (const float*)d_in[4];
  const float* eW2  = (const float*)d_in[5];
  const float* eb2  = (const float*)d_in[6];
  const float* elng = (const float*)d_in[7];
  const float* elnb = (const float*)d_in[8];
  const float* nW1  = (const float*)d_in[9];
  const float* nb1  = (const float*)d_in[10];
  const float* nW2  = (const float*)d_in[11];
  const float* nb2  = (const float*)d_in[12];
  const float* nlng = (const float*)d_in[13];
  const float* nlnb = (const float*)d_in[14];
  const int* src    = (const int*)d_in[15];
  const int* dst    = (const int*)d_in[16];
  float* out = (float*)d_out;

  unsigned char* wsb = (unsigned char*)d_ws;
  u32* cnt  = (u32*)(wsb + WS_COUNT);
  u32* rp   = (u32*)(wsb + WS_ROWPTR);
  u32* wloc = (u32*)(wsb + WS_WLOC);
  u32* bsum = (u32*)(wsb + WS_BSUM);
  u64* sorted = (u64*)(wsb + WS_SORTED);
  unsigned short* wp = (unsigned short*)(wsb + WS_WEIGHTS);
  unsigned short* esort = (unsigned short*)(wsb + WS_ESORT);

  const size_t REQUIRED = (size_t)WS_ESORT + (size_t)NEDGE * HDIM * 2;
  const bool fast = ws_size >= REQUIRED;

  hipMemsetAsync(cnt, 0, (size_t)NGRID * 4, stream);
  pack_weights<<<448, 256, 0, stream>>>(eW1, eW2, nW1, nW2, wp);
  hist_k<<<NEDGE / 256, 256, 0, stream>>>(dst, cnt);
  scan1<<<256, 256, 0, stream>>>(cnt, rp, bsum);
  scan2<<<1, 256, 0, stream>>>(bsum);
  scan3<<<256, 256, 0, stream>>>(rp, wloc, bsum);
  scatter_k<<<NEDGE / 256, 256, 0, stream>>>(src, dst, wloc, sorted);

  if (fast) {
    edge_kernel<true><<<NEDGE / 64, 256, 0, stream>>>(ef, grid, mesh, wp,
        eb1, eb2, elng, elnb, sorted, esort, nullptr);
    node_kernel<true><<<NGRID / 64, 256, 0, stream>>>(grid, wp,
        nb1, nb2, nlng, nlnb, rp, esort, nullptr, out);
  } else {
    hipMemsetAsync(out, 0, (size_t)NGRID * HDIM * sizeof(float), stream);
    edge_kernel<false><<<NEDGE / 64, 256, 0, stream>>>(ef, grid, mesh, wp,
        eb1, eb2, elng, elnb, sorted, nullptr, out);
    node_kernel<false><<<NGRID / 64, 256, 0, stream>>>(grid, wp,
        nb1, nb2, nlng, nlnb, rp, nullptr, out, out);
  }
}